// Round 6
// baseline (507.898 us; speedup 1.0000x reference)
//
#include <hip/hip_runtime.h>

typedef __bf16 bf16_t;
typedef bf16_t bf16x8 __attribute__((ext_vector_type(8)));
typedef float floatx4 __attribute__((ext_vector_type(4)));
typedef int i32x4 __attribute__((ext_vector_type(4)));

#define VMCNT(n) asm volatile("s_waitcnt vmcnt(" #n ")" ::: "memory")
#define LGKM(n)  asm volatile("s_waitcnt lgkmcnt(" #n ")" ::: "memory")
#define SCHED0   __builtin_amdgcn_sched_barrier(0)
// inline-asm LDS read: compiler-invisible; WE own lgkmcnt/vmcnt discipline.
#define DSR(dst, base, off) \
  asm volatile("ds_read_b128 %0, %1 offset:" #off : "=v"(dst) : "v"(base))

__device__ __forceinline__ void wg_barrier() {
  asm volatile("" ::: "memory");
  __builtin_amdgcn_s_barrier();
  asm volatile("" ::: "memory");
}

__device__ __forceinline__ void async_load16(const bf16_t* g, bf16_t* l) {
  __builtin_amdgcn_global_load_lds(
      (const __attribute__((address_space(1))) unsigned int*)g,
      (__attribute__((address_space(3))) unsigned int*)l, 16, 0, 0);
}

__device__ __forceinline__ unsigned lds_addr(const bf16_t* p) {
  return (unsigned)(unsigned long long)
      (__attribute__((address_space(3))) const bf16_t*)p;
}

// XCD swizzle: physical flat id -> logical flat id so each XCD works a
// CONTIGUOUS logical span (per-XCD L2 locality).
__device__ __forceinline__ int xcd_swizzle(int p, int total) {
  return (total % 8 == 0) ? (p & 7) * (total >> 3) + (p >> 3) : p;
}

// 16-MFMA cluster: one C-quadrant x K=64 (two K32 slices).
__device__ __forceinline__ void mfma16(
    floatx4 (&a4)[4][2],
    i32x4 x0, i32x4 x1, i32x4 x2, i32x4 x3,
    i32x4 x4, i32x4 x5, i32x4 x6, i32x4 x7,
    i32x4 y0, i32x4 y1, i32x4 y2, i32x4 y3)
{
  const bf16x8 A0[4] = {__builtin_bit_cast(bf16x8, x0), __builtin_bit_cast(bf16x8, x1),
                        __builtin_bit_cast(bf16x8, x2), __builtin_bit_cast(bf16x8, x3)};
  const bf16x8 A1[4] = {__builtin_bit_cast(bf16x8, x4), __builtin_bit_cast(bf16x8, x5),
                        __builtin_bit_cast(bf16x8, x6), __builtin_bit_cast(bf16x8, x7)};
  const bf16x8 B0[2] = {__builtin_bit_cast(bf16x8, y0), __builtin_bit_cast(bf16x8, y1)};
  const bf16x8 B1[2] = {__builtin_bit_cast(bf16x8, y2), __builtin_bit_cast(bf16x8, y3)};
  #pragma unroll
  for (int i = 0; i < 4; ++i)
    #pragma unroll
    for (int j = 0; j < 2; ++j) {
      a4[i][j] = __builtin_amdgcn_mfma_f32_16x16x32_bf16(A0[i], B0[j], a4[i][j], 0, 0, 0);
      a4[i][j] = __builtin_amdgcn_mfma_f32_16x16x32_bf16(A1[i], B1[j], a4[i][j], 0, 0, 0);
    }
}

// ===================== 256x256 8-phase GEMM core (R6) =====================
// R5 post-mortem: single-barrier + split lgkm was +5% only — all 8 waves
// still issue 96 ds_reads together then wait together: LDS service (~384cy)
// and MFMA (~154cy/SIMD) strictly ALTERNATE. R6: software-pipeline the reads
// ONE PHASE AHEAD. Reads for phase p+1 issue in phase p AFTER that phase's
// VMCNT; waits become "previous phase's reads done" (they had a full MFMA
// cluster of service time) -> LDS and MFMA pipes overlap.
// Read-issue schedule (tile u, buffer c=u&1, n=c^1):
//   (u-1)q3: A0(u)+B0(u) [12, buf c]   q0: B1(u)=Bhi [4, buf c]
//   q1: A1(u)=Ahi [8, buf c]           q2: none
// Stage schedule (unchanged, proven): q0:Bhi(u+1,n) q1:Ahi(u+1,n)
//   q2:Alo(u+2,c) q3:Blo(u+2,c)
// VMCNT(8) at EVERY phase start (after stage, BEFORE the DSRs) retires
// exactly the half the new reads need (re-counted for prologue, steady,
// u=0, and both tail tiles; VMCNT(0) only at (NT-2)q3). LGKM per phase:
// q0:(4) q1:(8) q2:(0) q3:none.
// WAR: reads now happen 1 phase EARLIER than R5's (which was safe) -> safer.
// Reads of p+1 pre-barrier vs other waves' phase-p stages: disjoint slots
// (checked per phase: read buf c, stages write buf n or other halves).
// LDS: elem = h*4096 + ks*8192 + row*32 + k, XOR k-group swizzle (0 conflicts
// measured): pre-swizzled global src, linear gload_lds dest,
// fk = ((lane>>4)^((fr>>1)&3))*8.
__device__ __forceinline__ void gemm_acc256(
    const bf16_t* __restrict__ A, const bf16_t* __restrict__ B,
    int K, int lda, int ldb, int bm, int bn, floatx4 (&acc)[4][4][2])
{
  __shared__ bf16_t lA[2][16384];
  __shared__ bf16_t lB[2][16384];
  const int t = threadIdx.x;
  const int lane = t & 63;
  const int w = t >> 6;
  const int wm64 = (w & 1) * 64;       // wave M offset within a 128-half
  const int wn32 = (w >> 1) * 32;      // wave N offset within a 128-half
  const int fr = lane & 15;
  const int fk = ((lane >> 4) ^ ((fr >> 1) & 3)) * 8;

  const int r0 = t >> 2;               // staging row within a 128-row half
  const int ksw = ((t & 3) ^ ((r0 >> 1) & 3)) * 8;   // pre-swizzled source k
  const long aRow = (long)(bm + r0) * lda + ksw;
  const long bRow = (long)(bn + r0) * ldb + ksw;
  const int NT = K >> 6;

  const unsigned baseA = lds_addr(&lA[0][0]);
  const unsigned baseB = lds_addr(&lB[0][0]);
  // per-thread fragment base (bytes); hi-half handled via +8192 imm offsets
  const unsigned fragA = baseA + (unsigned)(((wm64 + fr) * 32 + fk) * 2);
  const unsigned fragB = baseB + (unsigned)(((wn32 + fr) * 32 + fk) * 2);

  auto stageA = [&](int buf, int h, int u) {
    const bf16_t* s = A + aRow + (long)h * 128 * lda + u * 64;
    bf16_t* d = &lA[buf][h * 4096 + t * 8];
    async_load16(s, d);                 // k-slice 0
    async_load16(s + 32, d + 8192);     // k-slice 1
  };
  auto stageB = [&](int buf, int h, int u) {
    const bf16_t* s = B + bRow + (long)h * 128 * ldb + u * 64;
    bf16_t* d = &lB[buf][h * 4096 + t * 8];
    async_load16(s, d);
    async_load16(s + 32, d + 8192);
  };

  // prologue: [Alo0,Blo0,Bhi0,Ahi0,Alo1,Blo1] = 12 loads; VMCNT(8) -> Alo0,
  // Blo0 landed; then issue the tile-0 A0/B0 reads (pipeline head).
  stageA(0, 0, 0);
  stageB(0, 0, 0);
  stageB(0, 1, 0);
  stageA(0, 1, 0);
  stageA(1, 0, 1);
  stageB(1, 0, 1);
  VMCNT(8);
  wg_barrier();

  // fragment register banks (persist ACROSS phases/tiles — static names)
  i32x4 al0,al1,al2,al3,al4,al5,al6,al7;   // A lo-half (read at prev q3)
  i32x4 ah0,ah1,ah2,ah3,ah4,ah5,ah6,ah7;   // A hi-half (read at q1)
  i32x4 vl0,vl1,vl2,vl3;                   // B lo-half (read at prev q3)
  i32x4 vh0,vh1,vh2,vh3;                   // B hi-half (read at q0)

  {
    const unsigned aC = fragA, bC = fragB;   // buffer 0
    DSR(al0, aC, 0);     DSR(al1, aC, 1024);
    DSR(al2, aC, 2048);  DSR(al3, aC, 3072);
    DSR(al4, aC, 16384); DSR(al5, aC, 17408);
    DSR(al6, aC, 18432); DSR(al7, aC, 19456);
    DSR(vl0, bC, 0);     DSR(vl1, bC, 1024);
    DSR(vl2, bC, 16384); DSR(vl3, bC, 17408);
  }

  for (int u = 0; u < NT; ++u) {
    const int b = u & 1;
    const unsigned aC = fragA + (b ? 32768u : 0u);
    const unsigned bC = fragB + (b ? 32768u : 0u);
    const unsigned aN = fragA + (b ? 0u : 32768u);
    const unsigned bN = fragB + (b ? 0u : 32768u);

    // ---- phase 0: MFMA(A0,B0); read-ahead B1(u); stage Bhi(u+1) ----
    if (u + 1 < NT) stageB(b ^ 1, 1, u + 1);
    if (u < NT - 1) { VMCNT(8); }           // retires Bhi(u)
    DSR(vh0, bC, 8192);  DSR(vh1, bC, 9216);
    DSR(vh2, bC, 24576); DSR(vh3, bC, 25600);
    LGKM(4); SCHED0;                        // A0/B0 (prev q3 reads) done
    __builtin_amdgcn_s_setprio(1);
    mfma16(acc[0], al0,al1,al2,al3,al4,al5,al6,al7, vl0,vl1,vl2,vl3);
    __builtin_amdgcn_s_setprio(0);
    wg_barrier();

    // ---- phase 1: MFMA(A0,B1); read-ahead A1(u); stage Ahi(u+1) ----
    if (u + 1 < NT) stageA(b ^ 1, 1, u + 1);
    if (u < NT - 1) { VMCNT(8); }           // retires Ahi(u)
    DSR(ah0, aC, 8192);  DSR(ah1, aC, 9216);
    DSR(ah2, aC, 10240); DSR(ah3, aC, 11264);
    DSR(ah4, aC, 24576); DSR(ah5, aC, 25600);
    DSR(ah6, aC, 26624); DSR(ah7, aC, 27648);
    LGKM(8); SCHED0;                        // B1 done (only A1 outstanding)
    __builtin_amdgcn_s_setprio(1);
    mfma16(acc[1], al0,al1,al2,al3,al4,al5,al6,al7, vh0,vh1,vh2,vh3);
    __builtin_amdgcn_s_setprio(0);
    wg_barrier();

    // ---- phase 2: MFMA(A1,B0); no reads; stage Alo(u+2) ----
    if (u + 2 < NT) { stageA(b, 0, u + 2); VMCNT(8); }
    LGKM(0); SCHED0;                        // A1 done
    __builtin_amdgcn_s_setprio(1);
    mfma16(acc[2], ah0,ah1,ah2,ah3,ah4,ah5,ah6,ah7, vl0,vl1,vl2,vl3);
    __builtin_amdgcn_s_setprio(0);
    wg_barrier();

    // ---- phase 3: MFMA(A1,B1); read-ahead A0/B0(u+1); stage Blo(u+2) ----
    if (u + 2 < NT)       { stageB(b, 0, u + 2); VMCNT(8); }  // retires Blo(u+1)
    else if (u == NT - 2) { VMCNT(0); }                       // last tile all in
    if (u + 1 < NT) {
      DSR(al0, aN, 0);     DSR(al1, aN, 1024);
      DSR(al2, aN, 2048);  DSR(al3, aN, 3072);
      DSR(al4, aN, 16384); DSR(al5, aN, 17408);
      DSR(al6, aN, 18432); DSR(al7, aN, 19456);
      DSR(vl0, bN, 0);     DSR(vl1, bN, 1024);
      DSR(vl2, bN, 16384); DSR(vl3, bN, 17408);
    }
    // q3 needs no lgkm: B1 done at q1's LGKM(8), A1 at q2's LGKM(0)
    __builtin_amdgcn_s_setprio(1);
    mfma16(acc[3], ah0,ah1,ah2,ah3,ah4,ah5,ah6,ah7, vh0,vh1,vh2,vh3);
    __builtin_amdgcn_s_setprio(0);
    wg_barrier();
  }
}

// grid decode shared by batched kernels; 4x4 supertile order inside each
// XCD's contiguous span: working set = 4 A-panels + 4 B-panels (= 4 MB at
// qk's 256x1024 panels) -> fits one XCD L2, cuts over-fetch + vmcnt stalls.
__device__ __forceinline__ void decode_grid(int& z, int& by, int& bx) {
  const int gx = gridDim.x, gy = gridDim.y;
  const int total = gx * gy * gridDim.z;
  int P = ((int)blockIdx.z * gy + (int)blockIdx.y) * gx + (int)blockIdx.x;
  int L = xcd_swizzle(P, total);
  z = L / (gx * gy);
  const int rem = L - z * gx * gy;
  if ((gx & 3) == 0 && (gy & 3) == 0) {
    const int sid = rem >> 4, w16 = rem & 15;
    const int spx = gx >> 2;
    const int sty = sid / spx, stx = sid - sty * spx;
    bx = stx * 4 + (w16 & 3);
    by = sty * 4 + (w16 >> 2);
  } else if ((gx & 3) == 0) {            // gy not /4: fall back to row-major
    by = rem / gx; bx = rem - by * gx;
  } else {
    by = rem / gx; bx = rem - by * gx;
  }
}

// all three projections in ONE 768-block dispatch (256 tiles each).
// z=0: Q = x@Wq^T; z=1: K = x@Wk^T; z=2: Vt = Wv@x^T
__global__ __launch_bounds__(512, 2) void gemm_qkv(
    const bf16_t* __restrict__ xb, const bf16_t* __restrict__ Wqb,
    const bf16_t* __restrict__ Wkb, const bf16_t* __restrict__ Wvb,
    bf16_t* __restrict__ Q, bf16_t* __restrict__ Kp, bf16_t* __restrict__ Vt)
{
  const int L = xcd_swizzle((int)blockIdx.x, 768);
  const int z = L >> 8;             // 256 tiles per projection
  const int r = L & 255;
  const bf16_t *A, *B; bf16_t* C;
  int bm, bn, ldc;
  if (z == 0)      { A = xb;  B = Wqb; C = Q;  bm = (r >> 2) * 256; bn = (r & 3) * 256; ldc = 1024; }
  else if (z == 1) { A = xb;  B = Wkb; C = Kp; bm = (r >> 2) * 256; bn = (r & 3) * 256; ldc = 1024; }
  else             { A = Wvb; B = xb;  C = Vt; bm = (r & 3) * 256; bn = (r >> 2) * 256; ldc = 16384; }
  floatx4 acc[4][4][2] = {};
  gemm_acc256(A, B, 1024, 1024, 1024, bm, bn, acc);

  const int t = threadIdx.x;
  const int lane = t & 63;
  const int w = t >> 6;
  const int wm64 = (w & 1) * 64;
  const int wn32 = (w >> 1) * 32;
  const int rq = (lane >> 4) * 4;
  const int c15 = lane & 15;
  #pragma unroll
  for (int q = 0; q < 4; ++q) {
    const int rB = bm + (q >> 1) * 128 + wm64;
    const int cB = bn + (q & 1) * 128 + wn32;
    #pragma unroll
    for (int i = 0; i < 4; ++i)
      #pragma unroll
      for (int j = 0; j < 2; ++j)
        #pragma unroll
        for (int r2 = 0; r2 < 4; ++r2)
          C[(long)(rB + i * 16 + rq + r2) * ldc + cB + j * 16 + c15] =
              (bf16_t)acc[q][i][j][r2];
  }
}

// QK^T with fused exp + per-row partial sums.
// C[row,col] = exp(scale * Q[row,:].K[col,:]) in bf16; rowsum[row] += partials.
// No max-subtraction: logits ~ N(0,1), |logit| < ~7 -> exp safe in fp32.
// Epilogue: per-row partials reduced in LDS (rs[256], LDS atomics) then ONE
// global atomicAdd per row per block.
__global__ __launch_bounds__(512, 2) void gemm_qk_exp(
    const bf16_t* __restrict__ A, const bf16_t* __restrict__ B,
    bf16_t* __restrict__ C, float* __restrict__ rowsum,
    int K, int lda, int ldb, int ldc,
    long sA, long sB, long sC, long sR, float scale)
{
  __shared__ float rs[256];
  int z, by, bx;
  decode_grid(z, by, bx);
  A += (long)z * sA; B += (long)z * sB; C += (long)z * sC;
  rowsum += (long)z * sR;
  const int bm = by * 256, bn = bx * 256;
  if (threadIdx.x < 256) rs[threadIdx.x] = 0.f;   // visible after core's prologue barrier
  floatx4 acc[4][4][2] = {};
  gemm_acc256(A, B, K, lda, ldb, bm, bn, acc);

  const int t = threadIdx.x;
  const int lane = t & 63;
  const int w = t >> 6;
  const int wm64 = (w & 1) * 64;
  const int wn32 = (w >> 1) * 32;
  const int rq = (lane >> 4) * 4;
  const int c15 = lane & 15;
  #pragma unroll
  for (int q = 0; q < 4; ++q) {
    const int rB = bm + (q >> 1) * 128 + wm64;
    const int cB = bn + (q & 1) * 128 + wn32;
    #pragma unroll
    for (int i = 0; i < 4; ++i) {
      #pragma unroll
      for (int r2 = 0; r2 < 4; ++r2) {
        const int row = rB + i * 16 + rq + r2;
        float psum = 0.f;
        #pragma unroll
        for (int j = 0; j < 2; ++j) {
          const float e = __expf(acc[q][i][j][r2] * scale);
          const bf16_t h = (bf16_t)e;
          C[(long)row * ldc + cB + j * 16 + c15] = h;
          psum += (float)h;   // sum the ROUNDED values: numerator consistency
        }
        // 16 lanes hold this row's 32 cols (2 each)
        #pragma unroll
        for (int off = 8; off >= 1; off >>= 1)
          psum += __shfl_xor(psum, off, 16);
        if (c15 == 0) atomicAdd(&rs[row - bm], psum);   // LDS atomic
      }
    }
  }
  __syncthreads();
  if (t < 256) atomicAdd(&rowsum[bm + t], rs[t]);       // 1 global atomic/row
}

// PV with fused 1/rowsum normalization, fp32 output.
__global__ __launch_bounds__(512, 2) void gemm_pv(
    const bf16_t* __restrict__ A, const bf16_t* __restrict__ B,
    float* __restrict__ C, const float* __restrict__ rowsum,
    int K, int lda, int ldb, int ldc,
    long sA, long sB, long sC, long sR)
{
  int z, by, bx;
  decode_grid(z, by, bx);
  A += (long)z * sA; B += (long)z * sB; C += (long)z * sC;
  rowsum += (long)z * sR;
  const int bm = by * 256, bn = bx * 256;
  floatx4 acc[4][4][2] = {};
  gemm_acc256(A, B, K, lda, ldb, bm, bn, acc);

  const int t = threadIdx.x;
  const int lane = t & 63;
  const int w = t >> 6;
  const int wm64 = (w & 1) * 64;
  const int wn32 = (w >> 1) * 32;
  const int rq = (lane >> 4) * 4;
  const int c15 = lane & 15;
  #pragma unroll
  for (int q = 0; q < 4; ++q) {
    const int rB = bm + (q >> 1) * 128 + wm64;
    const int cB = bn + (q & 1) * 128 + wn32;
    #pragma unroll
    for (int i = 0; i < 4; ++i) {
      #pragma unroll
      for (int r2 = 0; r2 < 4; ++r2) {
        const int row = rB + i * 16 + rq + r2;
        const float inv = 1.0f / rowsum[row];
        #pragma unroll
        for (int j = 0; j < 2; ++j)
          C[(long)row * ldc + cB + j * 16 + c15] = acc[q][i][j][r2] * inv;
      }
    }
  }
}

// fp32 -> bf16 convert, 4 elems/thread; also zeroes the rowsum buffer
// (first 64 blocks, one float per thread) to save a dispatch.
__global__ __launch_bounds__(256) void cvt_f32_bf16(
    const float* __restrict__ in, bf16_t* __restrict__ out, long n,
    float* __restrict__ rowsum, int nrs)
{
  const int bid = blockIdx.x;
  if (rowsum && bid < 64) {
    const int k = bid * 256 + threadIdx.x;
    if (k < nrs) rowsum[k] = 0.f;
  }
  long i = ((long)bid * 256 + threadIdx.x) * 4;
  if (i + 3 < n) {
    float4 f = *(const float4*)&in[i];
    bf16_t o[4] = {(bf16_t)f.x, (bf16_t)f.y, (bf16_t)f.z, (bf16_t)f.w};
    *(ulong1*)&out[i] = *(ulong1*)o;
  }
}

// convert the three DxD weights in one dispatch (z selects the matrix)
__global__ __launch_bounds__(256) void cvt3_f32_bf16(
    const float* __restrict__ w0, const float* __restrict__ w1,
    const float* __restrict__ w2, bf16_t* __restrict__ o0,
    bf16_t* __restrict__ o1, bf16_t* __restrict__ o2)
{
  const float* in = (blockIdx.z == 0) ? w0 : (blockIdx.z == 1) ? w1 : w2;
  bf16_t* out = (blockIdx.z == 0) ? o0 : (blockIdx.z == 1) ? o1 : o2;
  long i = ((long)blockIdx.x * 256 + threadIdx.x) * 4;
  float4 f = *(const float4*)&in[i];
  bf16_t o[4] = {(bf16_t)f.x, (bf16_t)f.y, (bf16_t)f.z, (bf16_t)f.w};
  *(ulong1*)&out[i] = *(ulong1*)o;
}

// Workspace tiers (R1): scores alias xb+weights (dead after gemm_qkv),
// batched-path footprint 224.1 MiB; pair tier 160.1 MiB; per-batch 134.1.
//   layout: [score region nsc*SS | xb@0, W@SS][Q][K][Vt][rowsum]
extern "C" void kernel_launch(void* const* d_in, const int* in_sizes, int n_in,
                              void* d_out, int out_size, void* d_ws, size_t ws_size,
                              hipStream_t stream) {
  (void)in_sizes; (void)n_in; (void)out_size;
  const float* x  = (const float*)d_in[0];
  const float* Wq = (const float*)d_in[1];
  const float* Wk = (const float*)d_in[2];
  const float* Wv = (const float*)d_in[3];
  float* out = (float*)d_out;

  const long BS = 16384, D = 1024, S = 4096;
  const long SD = S * D;             // per-batch Q/K/V/out stride (elems)
  const long SS = S * S;             // one score buffer; == BS*D

  bf16_t* base = (bf16_t*)d_ws;
  bf16_t* Sc  = base;                // score region; Sc0 aliases xb
  bf16_t* xb  = base;                // dead after gemm_qkv
  bf16_t* Wqb = base + SS;           // dead after gemm_qkv (inside Sc1)
  bf16_t* Wkb = Wqb + D * D;
  bf16_t* Wvb = Wkb + D * D;

  // tier = number of live score buffers
  auto need = [&](long scElems) {
    return (size_t)(scElems + 3 * SS) * 2 + (size_t)BS * 4;
  };
  int nsc; long scE;
  if      (ws_size >= need(4 * SS)) { nsc = 4; scE = 4 * SS; }           // 224.1 MiB
  else if (ws_size >= need(2 * SS)) { nsc = 2; scE = 2 * SS; }           // 160.1 MiB
  else                              { nsc = 1; scE = SS + 3 * D * D; }   // 134.1 MiB

  bf16_t* Q  = base + scE;
  bf16_t* Kp = Q + SS;               // BS*D == SS elems each
  bf16_t* Vt = Kp + SS;              // Vt[d, b*4096 + s] = V[b,s,d]
  float* rowsum = (float*)(Vt + SS); // 16384 f32

  dim3 blk(256), blk512(512);
  cvt_f32_bf16<<<dim3((BS * D) / 1024), blk, 0, stream>>>(
      x, xb, BS * D, rowsum, (int)BS);
  cvt3_f32_bf16<<<dim3((D * D) / 1024, 1, 3), blk, 0, stream>>>(
      Wq, Wk, Wv, Wqb, Wkb, Wvb);

  // Q, K, Vt in one dispatch (768 blocks x 512 thr = 3 exact CU-waves)
  gemm_qkv<<<dim3(768), blk512, 0, stream>>>(xb, Wqb, Wkb, Wvb, Q, Kp, Vt);

  const float scale = 0.03125f;
  if (nsc == 4) {
    // all 4 batches in one qk and one pv dispatch (scores clobber xb+W: dead)
    gemm_qk_exp<<<dim3(16, 16, 4), blk512, 0, stream>>>(
        Q, Kp, Sc, rowsum, (int)D, (int)D, (int)D, (int)S,
        SD, SD, SS, S, scale);
    gemm_pv<<<dim3(4, 16, 4), blk512, 0, stream>>>(
        Sc, Vt, out, rowsum, (int)S, (int)S, (int)BS, (int)D,
        SS, S, SD, S);
  } else if (nsc == 2) {
    for (int p = 0; p < 2; ++p) {
      const long b0 = 2 * p;
      gemm_qk_exp<<<dim3(16, 16, 2), blk512, 0, stream>>>(
          Q + b0 * SD, Kp + b0 * SD, Sc, rowsum + b0 * S,
          (int)D, (int)D, (int)D, (int)S, SD, SD, SS, S, scale);
      gemm_pv<<<dim3(4, 16, 2), blk512, 0, stream>>>(
          Sc, Vt + b0 * S, out + b0 * SD, rowsum + b0 * S,
          (int)S, (int)S, (int)BS, (int)D, SS, S, SD, S);
    }
  } else {
    for (int b = 0; b < 4; ++b) {
      gemm_qk_exp<<<dim3(16, 16, 1), blk512, 0, stream>>>(
          Q + (long)b * SD, Kp + (long)b * SD, Sc, rowsum + (long)b * S,
          (int)D, (int)D, (int)D, (int)S, 0, 0, 0, 0, scale);
      gemm_pv<<<dim3(4, 16, 1), blk512, 0, stream>>>(
          Sc, Vt + (long)b * S, out + (long)b * SD, rowsum + (long)b * S,
          (int)S, (int)S, (int)BS, (int)D, 0, 0, 0, 0);
    }
  }
}

// Round 7
// 486.290 us; speedup vs baseline: 1.0444x; 1.0444x over previous
//
#include <hip/hip_runtime.h>

typedef __bf16 bf16_t;
typedef bf16_t bf16x8 __attribute__((ext_vector_type(8)));
typedef float floatx4 __attribute__((ext_vector_type(4)));
typedef int i32x4 __attribute__((ext_vector_type(4)));

#define VMCNT(n) asm volatile("s_waitcnt vmcnt(" #n ")" ::: "memory")
#define LGKM(n)  asm volatile("s_waitcnt lgkmcnt(" #n ")" ::: "memory")
#define SCHED0   __builtin_amdgcn_sched_barrier(0)
// inline-asm LDS read: compiler-invisible; WE own lgkmcnt/vmcnt discipline.
#define DSR(dst, base, off) \
  asm volatile("ds_read_b128 %0, %1 offset:" #off : "=v"(dst) : "v"(base))

__device__ __forceinline__ void wg_barrier() {
  asm volatile("" ::: "memory");
  __builtin_amdgcn_s_barrier();
  asm volatile("" ::: "memory");
}

__device__ __forceinline__ void async_load16(const bf16_t* g, bf16_t* l) {
  __builtin_amdgcn_global_load_lds(
      (const __attribute__((address_space(1))) unsigned int*)g,
      (__attribute__((address_space(3))) unsigned int*)l, 16, 0, 0);
}

__device__ __forceinline__ unsigned lds_addr(const bf16_t* p) {
  return (unsigned)(unsigned long long)
      (__attribute__((address_space(3))) const bf16_t*)p;
}

// XCD swizzle: physical flat id -> logical flat id so each XCD works a
// CONTIGUOUS logical span (per-XCD L2 locality).
__device__ __forceinline__ int xcd_swizzle(int p, int total) {
  return (total % 8 == 0) ? (p & 7) * (total >> 3) + (p >> 3) : p;
}

// 16-MFMA cluster: one C-quadrant x K=64 (two K32 slices).
__device__ __forceinline__ void mfma16(
    floatx4 (&a4)[4][2],
    i32x4 x0, i32x4 x1, i32x4 x2, i32x4 x3,
    i32x4 x4, i32x4 x5, i32x4 x6, i32x4 x7,
    i32x4 y0, i32x4 y1, i32x4 y2, i32x4 y3)
{
  const bf16x8 A0[4] = {__builtin_bit_cast(bf16x8, x0), __builtin_bit_cast(bf16x8, x1),
                        __builtin_bit_cast(bf16x8, x2), __builtin_bit_cast(bf16x8, x3)};
  const bf16x8 A1[4] = {__builtin_bit_cast(bf16x8, x4), __builtin_bit_cast(bf16x8, x5),
                        __builtin_bit_cast(bf16x8, x6), __builtin_bit_cast(bf16x8, x7)};
  const bf16x8 B0[2] = {__builtin_bit_cast(bf16x8, y0), __builtin_bit_cast(bf16x8, y1)};
  const bf16x8 B1[2] = {__builtin_bit_cast(bf16x8, y2), __builtin_bit_cast(bf16x8, y3)};
  #pragma unroll
  for (int i = 0; i < 4; ++i)
    #pragma unroll
    for (int j = 0; j < 2; ++j) {
      a4[i][j] = __builtin_amdgcn_mfma_f32_16x16x32_bf16(A0[i], B0[j], a4[i][j], 0, 0, 0);
      a4[i][j] = __builtin_amdgcn_mfma_f32_16x16x32_bf16(A1[i], B1[j], a4[i][j], 0, 0, 0);
    }
}

// ===================== 256x256 8-phase GEMM core (R7) =====================
// R4/R5/R6 schedule variants all plateau at ~30% MfmaUtil (+-3%). R7 = the
// highest-fidelity m201 replication: per phase (m201 order, TWO barriers):
//   {reads for THIS phase -> stage -> [LGKM(8) at the 12-read phase] ->
//    barrier -> LGKM(0) -> setprio(1) 16 MFMA setprio(0) -> barrier}
// vmcnt is counted ONCE PER K-TILE (m201: phases 4/8 only). Derived counts
// for our ring (2 loads/stage, stages q0:Bhi(u+1) q1:Ahi(u+1) q2:Alo(u+2)
// q3:Blo(u+2)):
//   prologue 12 loads -> VMCNT(4) retires Alo0,Blo0,Bhi0,Ahi0 (all tile 0);
//   q3(u) VMCNT(4): outstanding 12 -> retires Alo/Blo(u+1) + Bhi/Ahi(u+1)
//     (= everything tile u+1 reads), leaves Alo/Blo(u+2);
//   q3(NT-2) VMCNT(0) final drain; q3(NT-1) none.
// RAW: every staged half has >=1 {per-wave vmcnt -> barrier} between its
// stage and first read. WAR: reads of phase p and stages of phase p touch
// disjoint buffers/halves (checked per phase); 2 barriers/phase bound skew.
// Static 2-tile unroll: buffer base addrs are compile-time per call site.
// Fragment reuse (24 ds_read_b128/wave/tile): q0 reads A0(8)+B0(4),
// q1 reads B1(4), q2 reads A1(8), q3 none.
// LDS: elem = h*4096 + ks*8192 + row*32 + k, XOR k-group swizzle (0
// conflicts measured): pre-swizzled global src, linear gload_lds dest,
// fk = ((lane>>4)^((fr>>1)&3))*8.
__device__ __forceinline__ void gemm_acc256(
    const bf16_t* __restrict__ A, const bf16_t* __restrict__ B,
    int K, int lda, int ldb, int bm, int bn, floatx4 (&acc)[4][4][2])
{
  __shared__ bf16_t lA[2][16384];
  __shared__ bf16_t lB[2][16384];
  const int t = threadIdx.x;
  const int lane = t & 63;
  const int w = t >> 6;
  const int wm64 = (w & 1) * 64;       // wave M offset within a 128-half
  const int wn32 = (w >> 1) * 32;      // wave N offset within a 128-half
  const int fr = lane & 15;
  const int fk = ((lane >> 4) ^ ((fr >> 1) & 3)) * 8;

  const int r0 = t >> 2;               // staging row within a 128-row half
  const int ksw = ((t & 3) ^ ((r0 >> 1) & 3)) * 8;   // pre-swizzled source k
  const long aRow = (long)(bm + r0) * lda + ksw;
  const long bRow = (long)(bn + r0) * ldb + ksw;
  const int NT = K >> 6;

  const unsigned baseA = lds_addr(&lA[0][0]);
  const unsigned baseB = lds_addr(&lB[0][0]);
  // per-thread fragment base (bytes); hi-half handled via +8192 imm offsets
  const unsigned fragA = baseA + (unsigned)(((wm64 + fr) * 32 + fk) * 2);
  const unsigned fragB = baseB + (unsigned)(((wn32 + fr) * 32 + fk) * 2);

  auto stageA = [&](int buf, int h, int u) {
    const bf16_t* s = A + aRow + (long)h * 128 * lda + u * 64;
    bf16_t* d = &lA[buf][h * 4096 + t * 8];
    async_load16(s, d);                 // k-slice 0
    async_load16(s + 32, d + 8192);     // k-slice 1
  };
  auto stageB = [&](int buf, int h, int u) {
    const bf16_t* s = B + bRow + (long)h * 128 * ldb + u * 64;
    bf16_t* d = &lB[buf][h * 4096 + t * 8];
    async_load16(s, d);
    async_load16(s + 32, d + 8192);
  };

  // fragment register banks (static names; lifetimes within one tile)
  i32x4 al0,al1,al2,al3,al4,al5,al6,al7;   // A lo-half  (q0 -> q1)
  i32x4 ah0,ah1,ah2,ah3,ah4,ah5,ah6,ah7;   // A hi-half  (q2 -> q3)
  i32x4 vl0,vl1,vl2,vl3;                   // B lo-half  (q0 -> q2)
  i32x4 vh0,vh1,vh2,vh3;                   // B hi-half  (q1 -> q3)

  // one K64-tile = 4 phases, m201 order
  auto tile_body = [&](int u, unsigned aC, unsigned bC) {
    const int cb = u & 1, nb = cb ^ 1;
    // -------- q0: MFMA(A0,B0); reads A0+B0 (12); stage Bhi(u+1) --------
    DSR(al0, aC, 0);     DSR(al1, aC, 1024);
    DSR(al2, aC, 2048);  DSR(al3, aC, 3072);
    DSR(al4, aC, 16384); DSR(al5, aC, 17408);
    DSR(al6, aC, 18432); DSR(al7, aC, 19456);
    DSR(vl0, bC, 0);     DSR(vl1, bC, 1024);
    DSR(vl2, bC, 16384); DSR(vl3, bC, 17408);
    if (u + 1 < NT) stageB(nb, 1, u + 1);
    LGKM(8);                             // m201: cap DS queue at 12-read phase
    wg_barrier();
    LGKM(0); SCHED0;
    __builtin_amdgcn_s_setprio(1);
    mfma16(acc[0], al0,al1,al2,al3,al4,al5,al6,al7, vl0,vl1,vl2,vl3);
    __builtin_amdgcn_s_setprio(0);
    wg_barrier();
    // -------- q1: MFMA(A0,B1); reads B1 (4); stage Ahi(u+1) --------
    DSR(vh0, bC, 8192);  DSR(vh1, bC, 9216);
    DSR(vh2, bC, 24576); DSR(vh3, bC, 25600);
    if (u + 1 < NT) stageA(nb, 1, u + 1);
    wg_barrier();
    LGKM(0); SCHED0;
    __builtin_amdgcn_s_setprio(1);
    mfma16(acc[1], al0,al1,al2,al3,al4,al5,al6,al7, vh0,vh1,vh2,vh3);
    __builtin_amdgcn_s_setprio(0);
    wg_barrier();
    // -------- q2: MFMA(A1,B0); reads A1 (8); stage Alo(u+2) --------
    DSR(ah0, aC, 8192);  DSR(ah1, aC, 9216);
    DSR(ah2, aC, 10240); DSR(ah3, aC, 11264);
    DSR(ah4, aC, 24576); DSR(ah5, aC, 25600);
    DSR(ah6, aC, 26624); DSR(ah7, aC, 27648);
    if (u + 2 < NT) stageA(cb, 0, u + 2);
    wg_barrier();
    LGKM(0); SCHED0;
    __builtin_amdgcn_s_setprio(1);
    mfma16(acc[2], ah0,ah1,ah2,ah3,ah4,ah5,ah6,ah7, vl0,vl1,vl2,vl3);
    __builtin_amdgcn_s_setprio(0);
    wg_barrier();
    // -------- q3: MFMA(A1,B1); no reads; stage Blo(u+2); TILE vmcnt --------
    if (u + 2 < NT)       { stageB(cb, 0, u + 2); VMCNT(4); }
    else if (u == NT - 2) { VMCNT(0); }   // final drain, one tile early
    wg_barrier();
    // frags already lgkm'd at q1/q2; no wait needed
    __builtin_amdgcn_s_setprio(1);
    mfma16(acc[3], ah0,ah1,ah2,ah3,ah4,ah5,ah6,ah7, vh0,vh1,vh2,vh3);
    __builtin_amdgcn_s_setprio(0);
    wg_barrier();
  };

  // prologue: [Alo0,Blo0,Bhi0,Ahi0,Alo1,Blo1] = 12 loads; VMCNT(4) retires
  // the first 8 = ALL of tile 0 (q0..q2 reads covered before any wait).
  stageA(0, 0, 0);
  stageB(0, 0, 0);
  stageB(0, 1, 0);
  stageA(0, 1, 0);
  stageA(1, 0, 1);
  stageB(1, 0, 1);
  VMCNT(4);
  wg_barrier();

  for (int u = 0; u < NT; u += 2) {      // NT is even for all our shapes
    tile_body(u,     fragA,          fragB);
    tile_body(u + 1, fragA + 32768u, fragB + 32768u);
  }
}

// grid decode shared by batched kernels; 4x4 supertile order inside each
// XCD's contiguous span (R6: FETCH 147->98 MB on qk).
__device__ __forceinline__ void decode_grid(int& z, int& by, int& bx) {
  const int gx = gridDim.x, gy = gridDim.y;
  const int total = gx * gy * gridDim.z;
  int P = ((int)blockIdx.z * gy + (int)blockIdx.y) * gx + (int)blockIdx.x;
  int L = xcd_swizzle(P, total);
  z = L / (gx * gy);
  const int rem = L - z * gx * gy;
  if ((gx & 3) == 0 && (gy & 3) == 0) {
    const int sid = rem >> 4, w16 = rem & 15;
    const int spx = gx >> 2;
    const int sty = sid / spx, stx = sid - sty * spx;
    bx = stx * 4 + (w16 & 3);
    by = sty * 4 + (w16 >> 2);
  } else {
    by = rem / gx; bx = rem - by * gx;
  }
}

// all three projections in ONE 768-block dispatch (256 tiles each).
// z=0: Q = x@Wq^T; z=1: K = x@Wk^T; z=2: Vt = Wv@x^T
__global__ __launch_bounds__(512, 2) void gemm_qkv(
    const bf16_t* __restrict__ xb, const bf16_t* __restrict__ Wqb,
    const bf16_t* __restrict__ Wkb, const bf16_t* __restrict__ Wvb,
    bf16_t* __restrict__ Q, bf16_t* __restrict__ Kp, bf16_t* __restrict__ Vt)
{
  const int L = xcd_swizzle((int)blockIdx.x, 768);
  const int z = L >> 8;             // 256 tiles per projection
  const int r = L & 255;
  const bf16_t *A, *B; bf16_t* C;
  int bm, bn, ldc;
  if (z == 0)      { A = xb;  B = Wqb; C = Q;  bm = (r >> 2) * 256; bn = (r & 3) * 256; ldc = 1024; }
  else if (z == 1) { A = xb;  B = Wkb; C = Kp; bm = (r >> 2) * 256; bn = (r & 3) * 256; ldc = 1024; }
  else             { A = Wvb; B = xb;  C = Vt; bm = (r & 3) * 256; bn = (r >> 2) * 256; ldc = 16384; }
  floatx4 acc[4][4][2] = {};
  gemm_acc256(A, B, 1024, 1024, 1024, bm, bn, acc);

  const int t = threadIdx.x;
  const int lane = t & 63;
  const int w = t >> 6;
  const int wm64 = (w & 1) * 64;
  const int wn32 = (w >> 1) * 32;
  const int rq = (lane >> 4) * 4;
  const int c15 = lane & 15;
  #pragma unroll
  for (int q = 0; q < 4; ++q) {
    const int rB = bm + (q >> 1) * 128 + wm64;
    const int cB = bn + (q & 1) * 128 + wn32;
    #pragma unroll
    for (int i = 0; i < 4; ++i)
      #pragma unroll
      for (int j = 0; j < 2; ++j)
        #pragma unroll
        for (int r2 = 0; r2 < 4; ++r2)
          C[(long)(rB + i * 16 + rq + r2) * ldc + cB + j * 16 + c15] =
              (bf16_t)acc[q][i][j][r2];
  }
}

// QK^T with fused exp + per-row partial sums.
// C[row,col] = exp(scale * Q[row,:].K[col,:]) in bf16; rowsum[row] += partials.
// No max-subtraction: logits ~ N(0,1), |logit| < ~7 -> exp safe in fp32.
// Epilogue: per-row partials reduced in LDS (rs[256], LDS atomics) then ONE
// global atomicAdd per row per block.
__global__ __launch_bounds__(512, 2) void gemm_qk_exp(
    const bf16_t* __restrict__ A, const bf16_t* __restrict__ B,
    bf16_t* __restrict__ C, float* __restrict__ rowsum,
    int K, int lda, int ldb, int ldc,
    long sA, long sB, long sC, long sR, float scale)
{
  __shared__ float rs[256];
  int z, by, bx;
  decode_grid(z, by, bx);
  A += (long)z * sA; B += (long)z * sB; C += (long)z * sC;
  rowsum += (long)z * sR;
  const int bm = by * 256, bn = bx * 256;
  if (threadIdx.x < 256) rs[threadIdx.x] = 0.f;   // visible after core's prologue barrier
  floatx4 acc[4][4][2] = {};
  gemm_acc256(A, B, K, lda, ldb, bm, bn, acc);

  const int t = threadIdx.x;
  const int lane = t & 63;
  const int w = t >> 6;
  const int wm64 = (w & 1) * 64;
  const int wn32 = (w >> 1) * 32;
  const int rq = (lane >> 4) * 4;
  const int c15 = lane & 15;
  #pragma unroll
  for (int q = 0; q < 4; ++q) {
    const int rB = bm + (q >> 1) * 128 + wm64;
    const int cB = bn + (q & 1) * 128 + wn32;
    #pragma unroll
    for (int i = 0; i < 4; ++i) {
      #pragma unroll
      for (int r2 = 0; r2 < 4; ++r2) {
        const int row = rB + i * 16 + rq + r2;
        float psum = 0.f;
        #pragma unroll
        for (int j = 0; j < 2; ++j) {
          const float e = __expf(acc[q][i][j][r2] * scale);
          const bf16_t h = (bf16_t)e;
          C[(long)row * ldc + cB + j * 16 + c15] = h;
          psum += (float)h;   // sum the ROUNDED values: numerator consistency
        }
        // 16 lanes hold this row's 32 cols (2 each)
        #pragma unroll
        for (int off = 8; off >= 1; off >>= 1)
          psum += __shfl_xor(psum, off, 16);
        if (c15 == 0) atomicAdd(&rs[row - bm], psum);   // LDS atomic
      }
    }
  }
  __syncthreads();
  if (t < 256) atomicAdd(&rowsum[bm + t], rs[t]);       // 1 global atomic/row
}

// PV with fused 1/rowsum normalization, fp32 output.
__global__ __launch_bounds__(512, 2) void gemm_pv(
    const bf16_t* __restrict__ A, const bf16_t* __restrict__ B,
    float* __restrict__ C, const float* __restrict__ rowsum,
    int K, int lda, int ldb, int ldc,
    long sA, long sB, long sC, long sR)
{
  int z, by, bx;
  decode_grid(z, by, bx);
  A += (long)z * sA; B += (long)z * sB; C += (long)z * sC;
  rowsum += (long)z * sR;
  const int bm = by * 256, bn = bx * 256;
  floatx4 acc[4][4][2] = {};
  gemm_acc256(A, B, K, lda, ldb, bm, bn, acc);

  const int t = threadIdx.x;
  const int lane = t & 63;
  const int w = t >> 6;
  const int wm64 = (w & 1) * 64;
  const int wn32 = (w >> 1) * 32;
  const int rq = (lane >> 4) * 4;
  const int c15 = lane & 15;
  #pragma unroll
  for (int q = 0; q < 4; ++q) {
    const int rB = bm + (q >> 1) * 128 + wm64;
    const int cB = bn + (q & 1) * 128 + wn32;
    #pragma unroll
    for (int i = 0; i < 4; ++i) {
      #pragma unroll
      for (int r2 = 0; r2 < 4; ++r2) {
        const int row = rB + i * 16 + rq + r2;
        const float inv = 1.0f / rowsum[row];
        #pragma unroll
        for (int j = 0; j < 2; ++j)
          C[(long)row * ldc + cB + j * 16 + c15] = acc[q][i][j][r2] * inv;
      }
    }
  }
}

// fp32 -> bf16 convert, 4 elems/thread; also zeroes the rowsum buffer
// (first 64 blocks, one float per thread) to save a dispatch.
__global__ __launch_bounds__(256) void cvt_f32_bf16(
    const float* __restrict__ in, bf16_t* __restrict__ out, long n,
    float* __restrict__ rowsum, int nrs)
{
  const int bid = blockIdx.x;
  if (rowsum && bid < 64) {
    const int k = bid * 256 + threadIdx.x;
    if (k < nrs) rowsum[k] = 0.f;
  }
  long i = ((long)bid * 256 + threadIdx.x) * 4;
  if (i + 3 < n) {
    float4 f = *(const float4*)&in[i];
    bf16_t o[4] = {(bf16_t)f.x, (bf16_t)f.y, (bf16_t)f.z, (bf16_t)f.w};
    *(ulong1*)&out[i] = *(ulong1*)o;
  }
}

// convert the three DxD weights in one dispatch (z selects the matrix)
__global__ __launch_bounds__(256) void cvt3_f32_bf16(
    const float* __restrict__ w0, const float* __restrict__ w1,
    const float* __restrict__ w2, bf16_t* __restrict__ o0,
    bf16_t* __restrict__ o1, bf16_t* __restrict__ o2)
{
  const float* in = (blockIdx.z == 0) ? w0 : (blockIdx.z == 1) ? w1 : w2;
  bf16_t* out = (blockIdx.z == 0) ? o0 : (blockIdx.z == 1) ? o1 : o2;
  long i = ((long)blockIdx.x * 256 + threadIdx.x) * 4;
  float4 f = *(const float4*)&in[i];
  bf16_t o[4] = {(bf16_t)f.x, (bf16_t)f.y, (bf16_t)f.z, (bf16_t)f.w};
  *(ulong1*)&out[i] = *(ulong1*)o;
}

// Workspace tiers (R1): scores alias xb+weights (dead after gemm_qkv),
// batched-path footprint 224.1 MiB; pair tier 160.1 MiB; per-batch 134.1.
//   layout: [score region nsc*SS | xb@0, W@SS][Q][K][Vt][rowsum]
extern "C" void kernel_launch(void* const* d_in, const int* in_sizes, int n_in,
                              void* d_out, int out_size, void* d_ws, size_t ws_size,
                              hipStream_t stream) {
  (void)in_sizes; (void)n_in; (void)out_size;
  const float* x  = (const float*)d_in[0];
  const float* Wq = (const float*)d_in[1];
  const float* Wk = (const float*)d_in[2];
  const float* Wv = (const float*)d_in[3];
  float* out = (float*)d_out;

  const long BS = 16384, D = 1024, S = 4096;
  const long SD = S * D;             // per-batch Q/K/V/out stride (elems)
  const long SS = S * S;             // one score buffer; == BS*D

  bf16_t* base = (bf16_t*)d_ws;
  bf16_t* Sc  = base;                // score region; Sc0 aliases xb
  bf16_t* xb  = base;                // dead after gemm_qkv
  bf16_t* Wqb = base + SS;           // dead after gemm_qkv (inside Sc1)
  bf16_t* Wkb = Wqb + D * D;
  bf16_t* Wvb = Wkb + D * D;

  // tier = number of live score buffers
  auto need = [&](long scElems) {
    return (size_t)(scElems + 3 * SS) * 2 + (size_t)BS * 4;
  };
  int nsc; long scE;
  if      (ws_size >= need(4 * SS)) { nsc = 4; scE = 4 * SS; }           // 224.1 MiB
  else if (ws_size >= need(2 * SS)) { nsc = 2; scE = 2 * SS; }           // 160.1 MiB
  else                              { nsc = 1; scE = SS + 3 * D * D; }   // 134.1 MiB

  bf16_t* Q  = base + scE;
  bf16_t* Kp = Q + SS;               // BS*D == SS elems each
  bf16_t* Vt = Kp + SS;              // Vt[d, b*4096 + s] = V[b,s,d]
  float* rowsum = (float*)(Vt + SS); // 16384 f32

  dim3 blk(256), blk512(512);
  cvt_f32_bf16<<<dim3((BS * D) / 1024), blk, 0, stream>>>(
      x, xb, BS * D, rowsum, (int)BS);
  cvt3_f32_bf16<<<dim3((D * D) / 1024, 1, 3), blk, 0, stream>>>(
      Wq, Wk, Wv, Wqb, Wkb, Wvb);

  // Q, K, Vt in one dispatch (768 blocks x 512 thr = 3 exact CU-waves)
  gemm_qkv<<<dim3(768), blk512, 0, stream>>>(xb, Wqb, Wkb, Wvb, Q, Kp, Vt);

  const float scale = 0.03125f;
  if (nsc == 4) {
    // all 4 batches in one qk and one pv dispatch (scores clobber xb+W: dead)
    gemm_qk_exp<<<dim3(16, 16, 4), blk512, 0, stream>>>(
        Q, Kp, Sc, rowsum, (int)D, (int)D, (int)D, (int)S,
        SD, SD, SS, S, scale);
    gemm_pv<<<dim3(4, 16, 4), blk512, 0, stream>>>(
        Sc, Vt, out, rowsum, (int)S, (int)S, (int)BS, (int)D,
        SS, S, SD, S);
  } else if (nsc == 2) {
    for (int p = 0; p < 2; ++p) {
      const long b0 = 2 * p;
      gemm_qk_exp<<<dim3(16, 16, 2), blk512, 0, stream>>>(
          Q + b0 * SD, Kp + b0 * SD, Sc, rowsum + b0 * S,
          (int)D, (int)D, (int)D, (int)S, SD, SD, SS, S, scale);
      gemm_pv<<<dim3(4, 16, 2), blk512, 0, stream>>>(
          Sc, Vt + b0 * S, out + b0 * SD, rowsum + b0 * S,
          (int)S, (int)S, (int)BS, (int)D, SS, S, SD, S);
    }
  } else {
    for (int b = 0; b < 4; ++b) {
      gemm_qk_exp<<<dim3(16, 16, 1), blk512, 0, stream>>>(
          Q + (long)b * SD, Kp + (long)b * SD, Sc, rowsum + (long)b * S,
          (int)D, (int)D, (int)D, (int)S, 0, 0, 0, 0, scale);
      gemm_pv<<<dim3(4, 16, 1), blk512, 0, stream>>>(
          Sc, Vt + (long)b * S, out + (long)b * SD, rowsum + (long)b * S,
          (int)S, (int)S, (int)BS, (int)D, 0, 0, 0, 0);
    }
  }
}